// Round 8
// baseline (333.724 us; speedup 1.0000x reference)
//
#include <hip/hip_runtime.h>

// ---------------------------------------------------------------------------
// AML_TGNN: segment-mean over edges -> folded (msg-linear + GRU(h0=0)) -> cls
//
// R8 = R7 + accum A/B experiment. R5/R6/R7 showed accum pinned at ~184-194us
// regardless of occupancy/ILP/cache-policy -> per-CU divergent-gather rate
// wall ~0.68 lanes/ns/CU (≈64 slots x ~94ns L2 RTT). Test whether
// global_load_lds (per-lane global addr, LDS return path - no vL1D fill)
// bypasses the wall:
//   accum_a: buckets [0,128)   - R7 sc0 VGPR-return gathers (control)
//   accum_b: buckets [128,256) - glds gather into per-wave LDS rows
// Pre-commit: B < 0.85*A (B has ~9% less work) => glds wins, R9 all-glds.
//
// Packing: packet = (1<<52)|(qy<<26)|qx, q = round((v+8)*4096) in [0,2^16).
// Record u32 = src(20b) | dstLow(12b)<<20;  node = (bucket<<12)|dstLow.
// Overflow: records past bucket cap -> direct u64 atomic into partial0.
// ---------------------------------------------------------------------------

#define NBKT        256
#define BKT_SHIFT   12
#define DLOW_MASK   4095u
#define BKT_CAP     139264u
#define CHUNK       16384
#define BIN_THREADS 512
#define ACC_THREADS 1024
#define SPLIT       2
#define BKT_RANGE   4096
#define NODE_SPACE  (NBKT * BKT_RANGE)
#define GLDS_SLOTS  8

__device__ __forceinline__ unsigned long long expand_pkt(unsigned q)
{
    return (1ull << 52) | ((unsigned long long)(q >> 16) << 26)
                        | (unsigned long long)(q & 0xFFFFu);
}

__device__ __forceinline__ unsigned gather_sc0(const unsigned* p)
{
    return __hip_atomic_load(p, __ATOMIC_RELAXED, __HIP_MEMORY_SCOPE_AGENT);
}

// per-lane-address gather, LDS-return: lds[lane*4] <- *gaddr(lane)
__device__ __forceinline__ void glds4(const unsigned* g, unsigned* l)
{
    __builtin_amdgcn_global_load_lds(
        (const __attribute__((address_space(1))) void*)g,
        (__attribute__((address_space(3))) void*)l, 4, 0, 0);
}

// ---------------------------------------------------------------- prep -----
__global__ __launch_bounds__(64) void tgnn_prep_kernel(
    const float* __restrict__ W_msg, const float* __restrict__ b_msg,
    const float* __restrict__ W_ih,  const float* __restrict__ b_ih,
    const float* __restrict__ b_hh,  const float* __restrict__ W_cls,
    const float* __restrict__ b_cls, float* __restrict__ P)
{
    int j = threadIdx.x;
    if (j < 48) {
        float a0 = 0.f, a1 = 0.f, dd = 0.f;
        #pragma unroll
        for (int k = 0; k < 16; ++k) {
            float w = W_ih[j * 16 + k];
            a0 += w * W_msg[k * 2 + 0];
            a1 += w * W_msg[k * 2 + 1];
            dd += w * b_msg[k];
        }
        dd += b_ih[j];
        P[j]      = a0;
        P[48 + j] = a1;
        if (j < 16)      P[96 + j]         = dd + b_hh[j];
        else if (j < 32) P[112 + (j - 16)] = dd + b_hh[j];
        else             P[128 + (j - 32)] = dd;
    }
    if (j < 16) {
        P[144 + j] = b_hh[32 + j];
        P[160 + j] = W_cls[j];
        P[176 + j] = W_cls[16 + j];
    }
    if (j == 0) { P[192] = b_cls[0]; P[193] = b_cls[1]; }
}

// --------------------------------------------------------------- quant -----
__global__ __launch_bounds__(256) void tgnn_quant_kernel(
    const float2* __restrict__ nf, unsigned* __restrict__ qnf, int n)
{
    int i = blockIdx.x * blockDim.x + threadIdx.x;
    if (i >= n) return;
    float2 f = nf[i];
    float x = fminf(fmaxf(f.x, -7.9f), 7.9f);
    float y = fminf(fmaxf(f.y, -7.9f), 7.9f);
    unsigned qx = (unsigned)fmaf(x, 4096.0f, 32768.5f);
    unsigned qy = (unsigned)fmaf(y, 4096.0f, 32768.5f);
    qnf[i] = qx | (qy << 16);
}

// --------------------------------------------------------- cursor init -----
__global__ __launch_bounds__(256) void tgnn_cursor_init(unsigned* __restrict__ cursor)
{
    int b = threadIdx.x;
    cursor[b] = (unsigned)b * BKT_CAP;
}

// ----------------------------------------------------------------- bin -----
__global__ __launch_bounds__(BIN_THREADS) void tgnn_bin_kernel(
    const int* __restrict__ src, const int* __restrict__ dst,
    const unsigned* __restrict__ qnf,
    unsigned* __restrict__ rec, unsigned* __restrict__ cursor,
    unsigned long long* __restrict__ partial0,
    int n_edges)
{
    __shared__ unsigned cnt[NBKT];
    __shared__ unsigned pos[NBKT];
    __shared__ unsigned scur[NBKT];
    __shared__ unsigned gbase[NBKT];
    __shared__ unsigned stage[CHUNK];   // 64 KB

    int t  = threadIdx.x;
    int e0 = blockIdx.x * CHUNK;
    int ne = n_edges - e0;
    if (ne <= 0) return;
    if (ne > CHUNK) ne = CHUNK;
    int nv4 = (ne + 3) >> 2;

    const int4* s4p = (const int4*)(src + e0);
    const int4* d4p = (const int4*)(dst + e0);

    int4 dr[8], sr[8];
    #pragma unroll
    for (int j = 0; j < 8; ++j) {
        int i4 = j * BIN_THREADS + t;
        if (i4 < nv4) { dr[j] = d4p[i4]; sr[j] = s4p[i4]; }
    }

    if (t < NBKT) cnt[t] = 0;
    __syncthreads();

    #pragma unroll
    for (int j = 0; j < 8; ++j) {
        int base = 4 * (j * BIN_THREADS + t);
        if (base < ne) {
            int lim = ne - base;
            int dv[4] = { dr[j].x, dr[j].y, dr[j].z, dr[j].w };
            #pragma unroll
            for (int c = 0; c < 4; ++c)
                if (c < lim) atomicAdd(&cnt[((unsigned)dv[c]) >> BKT_SHIFT], 1u);
        }
    }
    __syncthreads();

    if (t < NBKT) pos[t] = cnt[t];
    __syncthreads();
    #pragma unroll
    for (int off = 1; off < NBKT; off <<= 1) {
        unsigned v = 0, a = 0;
        if (t < NBKT) { v = pos[t]; a = (t >= off) ? pos[t - off] : 0u; }
        __syncthreads();
        if (t < NBKT) pos[t] = v + a;
        __syncthreads();
    }
    if (t < NBKT) {
        unsigned myCnt  = cnt[t];
        unsigned myBase = pos[t] - myCnt;
        scur[t] = myBase;
        pos[t]  = myBase;
        gbase[t] = myCnt ? atomicAdd(&cursor[t], myCnt) : 0u;
    }
    __syncthreads();

    #pragma unroll
    for (int j = 0; j < 8; ++j) {
        int base = 4 * (j * BIN_THREADS + t);
        if (base < ne) {
            int lim = ne - base;
            int dv[4] = { dr[j].x, dr[j].y, dr[j].z, dr[j].w };
            int sv[4] = { sr[j].x, sr[j].y, sr[j].z, sr[j].w };
            #pragma unroll
            for (int c = 0; c < 4; ++c) if (c < lim) {
                unsigned d = (unsigned)dv[c];
                unsigned b = d >> BKT_SHIFT;
                unsigned p = atomicAdd(&scur[b], 1u);
                stage[p] = (unsigned)sv[c] | ((d & DLOW_MASK) << 20);
            }
        }
    }
    __syncthreads();

    int wave = t >> 6, lane = t & 63;
    for (int b = wave; b < NBKT; b += BIN_THREADS / 64) {
        unsigned n = cnt[b];
        if (!n) continue;
        unsigned sb = pos[b];
        unsigned gb = gbase[b];
        unsigned capEnd = (unsigned)(b + 1) * BKT_CAP;
        for (unsigned i = lane; i < n; i += 64) {
            unsigned r = stage[sb + i];
            unsigned slot = gb + i;
            if (slot < capEnd) {
                rec[slot] = r;
            } else {
                unsigned node = ((unsigned)b << BKT_SHIFT) | (r >> 20);
                atomicAdd(&partial0[node], expand_pkt(qnf[r & 0xFFFFFu]));
            }
        }
    }
}

// ------------------------------------------- accum A: sc0 VGPR gathers -----
__global__ __launch_bounds__(ACC_THREADS) void tgnn_accum_kernel(
    const unsigned* __restrict__ qnf,
    const unsigned* __restrict__ rec,
    const unsigned* __restrict__ cursor,
    unsigned long long* __restrict__ partial)
{
    __shared__ unsigned long long acc[BKT_RANGE];
    int b = blockIdx.x >> 1;            // buckets [0,128)
    int s = blockIdx.x & 1;
    int t = threadIdx.x;

    unsigned count = cursor[b] - (unsigned)b * BKT_CAP;
    if (count > BKT_CAP) count = BKT_CAP;
    unsigned mid = (count >> 1) & ~3u;
    unsigned i0 = s ? mid : 0u;
    unsigned i1 = s ? count : mid;

    unsigned long long* pb = partial + (size_t)s * NODE_SPACE + (size_t)b * BKT_RANGE;
    if (s == 0) {
        #pragma unroll
        for (int k = 0; k < BKT_RANGE / ACC_THREADS; ++k)
            acc[k * ACC_THREADS + t] = pb[k * ACC_THREADS + t];
    } else {
        #pragma unroll
        for (int k = 0; k < BKT_RANGE / ACC_THREADS; ++k)
            acc[k * ACC_THREADS + t] = 0ull;
    }
    __syncthreads();

    const unsigned* rb  = rec + (size_t)b * BKT_CAP;
    const int4*     rb4 = (const int4*)rb;

    unsigned v0 = i0 >> 2;
    unsigned v1 = i1 >> 2;
    unsigned v  = v0 + t;

    for (; v + ACC_THREADS < v1; v += 2 * ACC_THREADS) {
        int4 ra = rb4[v];
        int4 rc = rb4[v + ACC_THREADS];
        unsigned a0 = (unsigned)ra.x, a1 = (unsigned)ra.y;
        unsigned a2 = (unsigned)ra.z, a3 = (unsigned)ra.w;
        unsigned c0 = (unsigned)rc.x, c1 = (unsigned)rc.y;
        unsigned c2 = (unsigned)rc.z, c3 = (unsigned)rc.w;
        unsigned qa0 = gather_sc0(qnf + (a0 & 0xFFFFFu));
        unsigned qa1 = gather_sc0(qnf + (a1 & 0xFFFFFu));
        unsigned qa2 = gather_sc0(qnf + (a2 & 0xFFFFFu));
        unsigned qa3 = gather_sc0(qnf + (a3 & 0xFFFFFu));
        unsigned qc0 = gather_sc0(qnf + (c0 & 0xFFFFFu));
        unsigned qc1 = gather_sc0(qnf + (c1 & 0xFFFFFu));
        unsigned qc2 = gather_sc0(qnf + (c2 & 0xFFFFFu));
        unsigned qc3 = gather_sc0(qnf + (c3 & 0xFFFFFu));
        atomicAdd(&acc[a0 >> 20], expand_pkt(qa0));
        atomicAdd(&acc[a1 >> 20], expand_pkt(qa1));
        atomicAdd(&acc[a2 >> 20], expand_pkt(qa2));
        atomicAdd(&acc[a3 >> 20], expand_pkt(qa3));
        atomicAdd(&acc[c0 >> 20], expand_pkt(qc0));
        atomicAdd(&acc[c1 >> 20], expand_pkt(qc1));
        atomicAdd(&acc[c2 >> 20], expand_pkt(qc2));
        atomicAdd(&acc[c3 >> 20], expand_pkt(qc3));
    }
    for (; v < v1; v += ACC_THREADS) {
        int4 ra = rb4[v];
        unsigned a0 = (unsigned)ra.x, a1 = (unsigned)ra.y;
        unsigned a2 = (unsigned)ra.z, a3 = (unsigned)ra.w;
        unsigned qa0 = gather_sc0(qnf + (a0 & 0xFFFFFu));
        unsigned qa1 = gather_sc0(qnf + (a1 & 0xFFFFFu));
        unsigned qa2 = gather_sc0(qnf + (a2 & 0xFFFFFu));
        unsigned qa3 = gather_sc0(qnf + (a3 & 0xFFFFFu));
        atomicAdd(&acc[a0 >> 20], expand_pkt(qa0));
        atomicAdd(&acc[a1 >> 20], expand_pkt(qa1));
        atomicAdd(&acc[a2 >> 20], expand_pkt(qa2));
        atomicAdd(&acc[a3 >> 20], expand_pkt(qa3));
    }
    for (unsigned i = (v1 << 2) + t; i < i1; i += ACC_THREADS) {
        unsigned r = rb[i];
        atomicAdd(&acc[r >> 20], expand_pkt(gather_sc0(qnf + (r & 0xFFFFFu))));
    }
    __syncthreads();

    #pragma unroll
    for (int k = 0; k < BKT_RANGE / ACC_THREADS; ++k)
        pb[k * ACC_THREADS + t] = acc[k * ACC_THREADS + t];
}

// ----------------------------------- accum B: global_load_lds gathers -----
__global__ __launch_bounds__(ACC_THREADS) void tgnn_accum_glds_kernel(
    const unsigned* __restrict__ qnf,
    const unsigned* __restrict__ rec,
    const unsigned* __restrict__ cursor,
    unsigned long long* __restrict__ partial)
{
    __shared__ unsigned long long acc[BKT_RANGE];                   // 32 KB
    __shared__ unsigned gbuf[(ACC_THREADS / 64) * GLDS_SLOTS * 64]; // 32 KB
    int b = 128 + (blockIdx.x >> 1);    // buckets [128,256)
    int s = blockIdx.x & 1;
    int t = threadIdx.x;
    int wave = t >> 6, lane = t & 63;

    unsigned count = cursor[b] - (unsigned)b * BKT_CAP;
    if (count > BKT_CAP) count = BKT_CAP;
    unsigned mid = (count >> 1) & ~3u;
    unsigned i0 = s ? mid : 0u;
    unsigned i1 = s ? count : mid;

    unsigned long long* pb = partial + (size_t)s * NODE_SPACE + (size_t)b * BKT_RANGE;
    if (s == 0) {
        #pragma unroll
        for (int k = 0; k < BKT_RANGE / ACC_THREADS; ++k)
            acc[k * ACC_THREADS + t] = pb[k * ACC_THREADS + t];
    } else {
        #pragma unroll
        for (int k = 0; k < BKT_RANGE / ACC_THREADS; ++k)
            acc[k * ACC_THREADS + t] = 0ull;
    }
    __syncthreads();

    const unsigned* rb  = rec + (size_t)b * BKT_CAP;
    const int4*     rb4 = (const int4*)rb;
    unsigned* gw = &gbuf[wave * (GLDS_SLOTS * 64)];   // wave-private rows

    unsigned v0 = i0 >> 2;
    unsigned v1 = i1 >> 2;
    unsigned v  = v0 + t;

    for (; v + ACC_THREADS < v1; v += 2 * ACC_THREADS) {
        int4 ra = rb4[v];
        int4 rc = rb4[v + ACC_THREADS];
        unsigned r0 = (unsigned)ra.x, r1 = (unsigned)ra.y;
        unsigned r2 = (unsigned)ra.z, r3 = (unsigned)ra.w;
        unsigned r4 = (unsigned)rc.x, r5 = (unsigned)rc.y;
        unsigned r6 = (unsigned)rc.z, r7 = (unsigned)rc.w;
        glds4(qnf + (r0 & 0xFFFFFu), gw + 0 * 64);
        glds4(qnf + (r1 & 0xFFFFFu), gw + 1 * 64);
        glds4(qnf + (r2 & 0xFFFFFu), gw + 2 * 64);
        glds4(qnf + (r3 & 0xFFFFFu), gw + 3 * 64);
        glds4(qnf + (r4 & 0xFFFFFu), gw + 4 * 64);
        glds4(qnf + (r5 & 0xFFFFFu), gw + 5 * 64);
        glds4(qnf + (r6 & 0xFFFFFu), gw + 6 * 64);
        glds4(qnf + (r7 & 0xFFFFFu), gw + 7 * 64);
        __builtin_amdgcn_s_waitcnt(0x0F70);   // vmcnt(0), no lgkm/exp wait
        __builtin_amdgcn_sched_barrier(0);
        atomicAdd(&acc[r0 >> 20], expand_pkt(gw[0 * 64 + lane]));
        atomicAdd(&acc[r1 >> 20], expand_pkt(gw[1 * 64 + lane]));
        atomicAdd(&acc[r2 >> 20], expand_pkt(gw[2 * 64 + lane]));
        atomicAdd(&acc[r3 >> 20], expand_pkt(gw[3 * 64 + lane]));
        atomicAdd(&acc[r4 >> 20], expand_pkt(gw[4 * 64 + lane]));
        atomicAdd(&acc[r5 >> 20], expand_pkt(gw[5 * 64 + lane]));
        atomicAdd(&acc[r6 >> 20], expand_pkt(gw[6 * 64 + lane]));
        atomicAdd(&acc[r7 >> 20], expand_pkt(gw[7 * 64 + lane]));
    }
    for (; v < v1; v += ACC_THREADS) {
        int4 ra = rb4[v];
        unsigned r0 = (unsigned)ra.x, r1 = (unsigned)ra.y;
        unsigned r2 = (unsigned)ra.z, r3 = (unsigned)ra.w;
        glds4(qnf + (r0 & 0xFFFFFu), gw + 0 * 64);
        glds4(qnf + (r1 & 0xFFFFFu), gw + 1 * 64);
        glds4(qnf + (r2 & 0xFFFFFu), gw + 2 * 64);
        glds4(qnf + (r3 & 0xFFFFFu), gw + 3 * 64);
        __builtin_amdgcn_s_waitcnt(0x0F70);
        __builtin_amdgcn_sched_barrier(0);
        atomicAdd(&acc[r0 >> 20], expand_pkt(gw[0 * 64 + lane]));
        atomicAdd(&acc[r1 >> 20], expand_pkt(gw[1 * 64 + lane]));
        atomicAdd(&acc[r2 >> 20], expand_pkt(gw[2 * 64 + lane]));
        atomicAdd(&acc[r3 >> 20], expand_pkt(gw[3 * 64 + lane]));
    }
    for (unsigned i = (v1 << 2) + t; i < i1; i += ACC_THREADS) {
        unsigned r = rb[i];
        atomicAdd(&acc[r >> 20], expand_pkt(gather_sc0(qnf + (r & 0xFFFFFu))));
    }
    __syncthreads();

    #pragma unroll
    for (int k = 0; k < BKT_RANGE / ACC_THREADS; ++k)
        pb[k * ACC_THREADS + t] = acc[k * ACC_THREADS + t];
}

// ---------------------------------------------------------- merge+node -----
__global__ __launch_bounds__(256) void tgnn_merge_node_kernel(
    const float2* __restrict__ nf,
    const unsigned long long* __restrict__ partial,
    const float* __restrict__ P,
    float2* __restrict__ out, int n_nodes)
{
    __shared__ float p[194];
    for (int k = threadIdx.x; k < 194; k += 256) p[k] = P[k];
    __syncthreads();

    int i = blockIdx.x * 256 + threadIdx.x;
    if (i >= n_nodes) return;

    unsigned long long v = partial[i] + partial[NODE_SPACE + i];
    unsigned c = (unsigned)(v >> 52);
    float a0, a1;
    if (c > 0) {
        float inv = 1.0f / (float)c;
        float X = (float)(unsigned)(v & 0x3FFFFFFull);
        float Y = (float)(unsigned)((v >> 26) & 0x3FFFFFFull);
        a0 = X * inv * (1.0f / 4096.0f) - 8.0f;
        a1 = Y * inv * (1.0f / 4096.0f) - 8.0f;
    } else {
        float2 f = nf[i];
        a0 = f.x;
        a1 = f.y;
    }

    float o0 = p[192], o1 = p[193];
    #pragma unroll
    for (int j = 0; j < 16; ++j) {
        float gr = fmaf(p[j],      a0, fmaf(p[48 + j], a1, p[96 + j]));
        float gz = fmaf(p[16 + j], a0, fmaf(p[64 + j], a1, p[112 + j]));
        float gn = fmaf(p[32 + j], a0, fmaf(p[80 + j], a1, p[128 + j]));
        float r  = 1.0f / (1.0f + __expf(-gr));
        float z  = 1.0f / (1.0f + __expf(-gz));
        float tt = fmaf(r, p[144 + j], gn);
        tt = fminf(fmaxf(tt, -12.0f), 12.0f);
        float e  = __expf(2.0f * tt);
        float n  = (e - 1.0f) / (e + 1.0f);
        float h  = (1.0f - z) * n;
        o0 = fmaf(p[160 + j], h, o0);
        o1 = fmaf(p[176 + j], h, o1);
    }
    out[i] = make_float2(o0, o1);
}

// ----------------------------------------------- fallback (R3 atomic path) --
__global__ __launch_bounds__(256) void tgnn_edge_kernel(
    const unsigned* __restrict__ qnf,
    const int* __restrict__ src,
    const int* __restrict__ dst,
    unsigned long long* __restrict__ pack,
    int n_edges)
{
    int tid    = blockIdx.x * blockDim.x + threadIdx.x;
    int stride = gridDim.x * blockDim.x;
    int n4     = n_edges >> 2;
    const int4* __restrict__ src4 = (const int4*)src;
    const int4* __restrict__ dst4 = (const int4*)dst;
    for (int i = tid; i < n4; i += stride) {
        int4 s = src4[i];
        int4 d = dst4[i];
        unsigned q0 = qnf[s.x], q1 = qnf[s.y], q2 = qnf[s.z], q3 = qnf[s.w];
        atomicAdd(&pack[d.x], expand_pkt(q0));
        atomicAdd(&pack[d.y], expand_pkt(q1));
        atomicAdd(&pack[d.z], expand_pkt(q2));
        atomicAdd(&pack[d.w], expand_pkt(q3));
    }
    for (int e = (n4 << 2) + tid; e < n_edges; e += stride)
        atomicAdd(&pack[dst[e]], expand_pkt(qnf[src[e]]));
}

__global__ __launch_bounds__(256) void tgnn_node_kernel(
    const float2* __restrict__ nf,
    const unsigned long long* __restrict__ pack,
    const float* __restrict__ P,
    float2* __restrict__ out, int n_nodes)
{
    __shared__ float p[194];
    for (int k = threadIdx.x; k < 194; k += 256) p[k] = P[k];
    __syncthreads();
    int i = blockIdx.x * 256 + threadIdx.x;
    if (i >= n_nodes) return;
    unsigned long long v = pack[i];
    unsigned c = (unsigned)(v >> 52);
    float a0, a1;
    if (c > 0) {
        float inv = 1.0f / (float)c;
        float X = (float)(unsigned)(v & 0x3FFFFFFull);
        float Y = (float)(unsigned)((v >> 26) & 0x3FFFFFFull);
        a0 = X * inv * (1.0f / 4096.0f) - 8.0f;
        a1 = Y * inv * (1.0f / 4096.0f) - 8.0f;
    } else {
        float2 f = nf[i];
        a0 = f.x; a1 = f.y;
    }
    float o0 = p[192], o1 = p[193];
    #pragma unroll
    for (int j = 0; j < 16; ++j) {
        float gr = fmaf(p[j],      a0, fmaf(p[48 + j], a1, p[96 + j]));
        float gz = fmaf(p[16 + j], a0, fmaf(p[64 + j], a1, p[112 + j]));
        float gn = fmaf(p[32 + j], a0, fmaf(p[80 + j], a1, p[128 + j]));
        float r  = 1.0f / (1.0f + __expf(-gr));
        float z  = 1.0f / (1.0f + __expf(-gz));
        float tt = fmaf(r, p[144 + j], gn);
        tt = fminf(fmaxf(tt, -12.0f), 12.0f);
        float e  = __expf(2.0f * tt);
        float n  = (e - 1.0f) / (e + 1.0f);
        float h  = (1.0f - z) * n;
        o0 = fmaf(p[160 + j], h, o0);
        o1 = fmaf(p[176 + j], h, o1);
    }
    out[i] = make_float2(o0, o1);
}

// -------------------------------------------------------------- launch -----
extern "C" void kernel_launch(void* const* d_in, const int* in_sizes, int n_in,
                              void* d_out, int out_size, void* d_ws, size_t ws_size,
                              hipStream_t stream)
{
    const float* nf    = (const float*)d_in[0];
    const int*   ei    = (const int*)d_in[1];
    const float* W_msg = (const float*)d_in[2];
    const float* b_msg = (const float*)d_in[3];
    const float* W_ih  = (const float*)d_in[4];
    const float* b_ih  = (const float*)d_in[6];
    const float* b_hh  = (const float*)d_in[7];
    const float* W_cls = (const float*)d_in[8];
    const float* b_cls = (const float*)d_in[9];
    float* out = (float*)d_out;

    const int N = in_sizes[0] / 2;
    const int E = in_sizes[1] / 2;
    const int qBlocks = (N + 255) / 256;

    size_t off = 0;
    auto take = [&](size_t bytes) { size_t o = off; off = (off + bytes + 255) & ~(size_t)255; return o; };
    size_t partialOff = take((size_t)SPLIT * NODE_SPACE * 8);
    size_t recOff     = take((size_t)NBKT * BKT_CAP * 4);
    size_t qnfOff     = take((size_t)N * 4);
    size_t curOff     = take((size_t)NBKT * 4);
    size_t pOff       = take(194 * 4);
    size_t need = off;

    char* ws = (char*)d_ws;

    if (ws_size >= need) {
        unsigned long long* partial = (unsigned long long*)(ws + partialOff);
        unsigned* rec    = (unsigned*)(ws + recOff);
        unsigned* qnf    = (unsigned*)(ws + qnfOff);
        unsigned* cursor = (unsigned*)(ws + curOff);
        float*    P      = (float*)(ws + pOff);

        (void)hipMemsetAsync(partial, 0, (size_t)NODE_SPACE * 8, stream);

        tgnn_cursor_init<<<1, 256, 0, stream>>>(cursor);
        tgnn_prep_kernel<<<1, 64, 0, stream>>>(W_msg, b_msg, W_ih, b_ih, b_hh,
                                               W_cls, b_cls, P);
        tgnn_quant_kernel<<<qBlocks, 256, 0, stream>>>((const float2*)nf, qnf, N);

        int binBlocks = (E + CHUNK - 1) / CHUNK;
        tgnn_bin_kernel<<<binBlocks, BIN_THREADS, 0, stream>>>(ei, ei + E, qnf, rec,
                                                               cursor, partial, E);

        // A/B: buckets [0,128) via VGPR sc0 gathers, [128,256) via glds
        tgnn_accum_kernel<<<128 * SPLIT, ACC_THREADS, 0, stream>>>(qnf, rec,
                                                                   cursor, partial);
        tgnn_accum_glds_kernel<<<128 * SPLIT, ACC_THREADS, 0, stream>>>(qnf, rec,
                                                                        cursor, partial);

        tgnn_merge_node_kernel<<<qBlocks, 256, 0, stream>>>((const float2*)nf, partial,
                                                            P, (float2*)out, N);
    } else {
        unsigned long long* pack = (unsigned long long*)ws;
        unsigned* qnf = (unsigned*)(ws + (size_t)N * 8);
        float*    P   = (float*)(ws + (size_t)N * 12);

        (void)hipMemsetAsync(pack, 0, (size_t)N * 8, stream);
        tgnn_prep_kernel<<<1, 64, 0, stream>>>(W_msg, b_msg, W_ih, b_ih, b_hh,
                                               W_cls, b_cls, P);
        tgnn_quant_kernel<<<qBlocks, 256, 0, stream>>>((const float2*)nf, qnf, N);
        tgnn_edge_kernel<<<2048, 256, 0, stream>>>(qnf, ei, ei + E, pack, E);
        tgnn_node_kernel<<<qBlocks, 256, 0, stream>>>((const float2*)nf, pack,
                                                      P, (float2*)out, N);
    }
}